// Round 2
// baseline (2229.570 us; speedup 1.0000x reference)
//
#include <hip/hip_runtime.h>
#include <math.h>

// GraphUnet on MI355X.
// Strategy:
//  - Every GCN layer (A@X)@W+b is computed as A@(X@W)+b  (associativity):
//    the 64x64 "small" gemm happens at pooled size, then ONE heavy pass
//    A0[rows gathered] @ Zn (Zn = column-scatter of Z into full 8192x64).
//  - Pooled adjacency A[idx][:,idx] is NEVER materialized: composed index
//    arrays I1..I4 gather rows of the ORIGINAL A; scatter handles columns.
//    (valid because I_{l+1} = I_l[local_idx], so A_l[:, lidx[c]] = A0[I_l, I_{l+1}[c]])
//  - top-k via exact rank counting (matches jax.lax.top_k set + ordering:
//    rank = #{j: s_j > s_i or (s_j == s_i and j < i)}; bijective -> every
//    output row written exactly once).
//  - Heavy gemm: fp32 (no fp32 MFMA on CDNA4), BM=128 rows x 64 cols,
//    BK=32, 256 threads, 4x8 micro-tile, split-K into partial buffers,
//    deterministic reduce fused with bias + residual (unpool skip-add).

#define N0 8192
#define BM 128
#define BK 32

// ---------------------------------------------------------------- small gemm
// Z[oidx?oidx[r]:r] = X1[r,:]@W1 (+ X2[r,:]@W2)   rows x 64, K=64 (per input)
__global__ __launch_bounds__(256) void k_small_gemm(
    const float* __restrict__ X1, const float* __restrict__ W1,
    const float* __restrict__ X2, const float* __restrict__ W2,
    const int* __restrict__ oidx, float* __restrict__ Z, int rows)
{
    __shared__ __align__(16) float Ws1[64][64];
    __shared__ __align__(16) float Ws2[64][64];
    __shared__ __align__(16) float Xs1[32][64];
    __shared__ __align__(16) float Xs2[32][64];
    const int tid = threadIdx.x;
    const int r0 = blockIdx.x * 32;

#pragma unroll
    for (int l = 0; l < 4; ++l) {
        int idx = tid + 256 * l;            // float4 index 0..1023
        int rw = idx >> 4, c4 = (idx & 15) * 4;
        *(float4*)&Ws1[rw][c4] = *(const float4*)(W1 + rw * 64 + c4);
    }
    if (X2) {
#pragma unroll
        for (int l = 0; l < 4; ++l) {
            int idx = tid + 256 * l;
            int rw = idx >> 4, c4 = (idx & 15) * 4;
            *(float4*)&Ws2[rw][c4] = *(const float4*)(W2 + rw * 64 + c4);
        }
    }
#pragma unroll
    for (int l = 0; l < 2; ++l) {
        int idx = tid + 256 * l;            // 0..511
        int rl = idx >> 4, c4 = (idx & 15) * 4;
        int r = r0 + rl;
        float4 v = make_float4(0.f, 0.f, 0.f, 0.f);
        if (r < rows) v = *(const float4*)(X1 + (size_t)r * 64 + c4);
        *(float4*)&Xs1[rl][c4] = v;
        if (X2) {
            float4 v2 = make_float4(0.f, 0.f, 0.f, 0.f);
            if (r < rows) v2 = *(const float4*)(X2 + (size_t)r * 64 + c4);
            *(float4*)&Xs2[rl][c4] = v2;
        }
    }
    __syncthreads();

    const int c = tid & 63;
    const int rg = tid >> 6;                // rows rg*8 .. rg*8+7
    float acc[8] = {0, 0, 0, 0, 0, 0, 0, 0};
#pragma unroll
    for (int k4 = 0; k4 < 16; ++k4) {
        float w0 = Ws1[k4 * 4 + 0][c], w1 = Ws1[k4 * 4 + 1][c];
        float w2 = Ws1[k4 * 4 + 2][c], w3 = Ws1[k4 * 4 + 3][c];
#pragma unroll
        for (int j = 0; j < 8; ++j) {
            float4 x = *(const float4*)&Xs1[rg * 8 + j][k4 * 4];
            acc[j] += x.x * w0 + x.y * w1 + x.z * w2 + x.w * w3;
        }
        if (X2) {
            float u0 = Ws2[k4 * 4 + 0][c], u1 = Ws2[k4 * 4 + 1][c];
            float u2 = Ws2[k4 * 4 + 2][c], u3 = Ws2[k4 * 4 + 3][c];
#pragma unroll
            for (int j = 0; j < 8; ++j) {
                float4 x = *(const float4*)&Xs2[rg * 8 + j][k4 * 4];
                acc[j] += x.x * u0 + x.y * u1 + x.z * u2 + x.w * u3;
            }
        }
    }
#pragma unroll
    for (int j = 0; j < 8; ++j) {
        int r = r0 + rg * 8 + j;
        if (r < rows) {
            int ro = oidx ? oidx[r] : r;
            Z[(size_t)ro * 64 + c] = acc[j];
        }
    }
}

// ----------------------------------------------------------------- big gemm
// P[splitS][r][c] = sum_{k in chunk} A[g(r),k] * Zn[k][c]
__global__ __launch_bounds__(256) void k_big_gemm(
    const float* __restrict__ A, const float* __restrict__ Zn,
    const int* __restrict__ gidx, float* __restrict__ P,
    int rows, int kchunk)
{
    __shared__ __align__(16) float As[BK][BM + 4];   // transposed A tile
    __shared__ __align__(16) float Xs[BK][64];
    const int tid = threadIdx.x;
    const int tx = tid & 7;          // cols tx*8 .. tx*8+7
    const int ty = tid >> 3;         // rows ty*4 .. ty*4+3
    const int r0 = blockIdx.x * BM;
    const int k0 = blockIdx.y * kchunk;

    const int lm = tid >> 3;         // load row-in-tile base (0..31)
    const int lkg = tid & 7;         // k-group within BK
    int lrow[4];
#pragma unroll
    for (int l = 0; l < 4; ++l) {
        int r = r0 + lm + 32 * l;
        int rr = (r < rows) ? r : (rows - 1);
        lrow[l] = gidx ? gidx[rr] : rr;
    }

    float acc[4][8];
#pragma unroll
    for (int i = 0; i < 4; ++i)
#pragma unroll
        for (int j = 0; j < 8; ++j) acc[i][j] = 0.f;

    for (int kt = 0; kt < kchunk; kt += BK) {
        const int kb = k0 + kt;
#pragma unroll
        for (int l = 0; l < 4; ++l) {
            const float4 v =
                *(const float4*)(A + (size_t)lrow[l] * N0 + kb + lkg * 4);
            const int m = lm + 32 * l;
            As[lkg * 4 + 0][m] = v.x;
            As[lkg * 4 + 1][m] = v.y;
            As[lkg * 4 + 2][m] = v.z;
            As[lkg * 4 + 3][m] = v.w;
        }
#pragma unroll
        for (int l = 0; l < 2; ++l) {
            int idx = tid + 256 * l;
            int kk = idx >> 4, c4 = (idx & 15) * 4;
            *(float4*)&Xs[kk][c4] =
                *(const float4*)(Zn + (size_t)(kb + kk) * 64 + c4);
        }
        __syncthreads();
#pragma unroll
        for (int kk = 0; kk < BK; ++kk) {
            float4 a = *(const float4*)&As[kk][ty * 4];
            float4 b0 = *(const float4*)&Xs[kk][tx * 8];
            float4 b1 = *(const float4*)&Xs[kk][tx * 8 + 4];
            float av[4] = {a.x, a.y, a.z, a.w};
            float bv[8] = {b0.x, b0.y, b0.z, b0.w, b1.x, b1.y, b1.z, b1.w};
#pragma unroll
            for (int i = 0; i < 4; ++i)
#pragma unroll
                for (int j = 0; j < 8; ++j) acc[i][j] += av[i] * bv[j];
        }
        __syncthreads();
    }

    float* Pp = P + (size_t)blockIdx.y * rows * 64;
#pragma unroll
    for (int i = 0; i < 4; ++i) {
        int r = r0 + ty * 4 + i;
        if (r < rows) {
            float4 v0 = make_float4(acc[i][0], acc[i][1], acc[i][2], acc[i][3]);
            float4 v1 = make_float4(acc[i][4], acc[i][5], acc[i][6], acc[i][7]);
            *(float4*)(Pp + (size_t)r * 64 + tx * 8) = v0;
            *(float4*)(Pp + (size_t)r * 64 + tx * 8 + 4) = v1;
        }
    }
}

// ------------------------------------------------------------------- reduce
// Xout[r][c] = bias[c] (+ resid[r][c]) + sum_s P[s][r][c]
__global__ __launch_bounds__(256) void k_reduce(
    const float* __restrict__ P, int splitK, int rows,
    const float* __restrict__ bias, const float* __restrict__ resid,
    float* __restrict__ Xout)
{
    int t = blockIdx.x * 256 + threadIdx.x;
    if (t >= rows * 16) return;
    int r = t >> 4, c4 = (t & 15) * 4;
    float4 s = *(const float4*)(bias + c4);
    if (resid) {
        float4 d = *(const float4*)(resid + (size_t)r * 64 + c4);
        s.x += d.x; s.y += d.y; s.z += d.z; s.w += d.w;
    }
    const float* p = P + (size_t)r * 64 + c4;
    for (int sp = 0; sp < splitK; ++sp) {
        float4 v = *(const float4*)(p + (size_t)sp * rows * 64);
        s.x += v.x; s.y += v.y; s.z += v.z; s.w += v.w;
    }
    *(float4*)(Xout + (size_t)r * 64 + c4) = s;
}

// -------------------------------------------------------- fused pool + rank
// Each block: (1) cooperatively computes ALL n scores into LDS
// (deterministic -> identical across blocks), (2) each thread ranks one row;
// if rank < ksel, writes compacted row (scaled by score) + composed index.
__global__ __launch_bounds__(256) void k_pool_rank(
    const float* __restrict__ X, const float* __restrict__ w,
    const float* __restrict__ bp, int n, int ksel,
    const int* __restrict__ Iold, float* __restrict__ Xp,
    int* __restrict__ Inew)
{
    extern __shared__ float ss[];            // npad floats
    __shared__ float ws[64];
    if (threadIdx.x < 64) ws[threadIdx.x] = w[threadIdx.x];
    __syncthreads();
    const int npad = (n + 3) & ~3;
    const float b = bp[0];
    for (int i = threadIdx.x; i < npad; i += 256) {
        float s = -1.0f;
        if (i < n) {
            const float* x = X + (size_t)i * 64;
            float acc = 0.f;
#pragma unroll
            for (int k4 = 0; k4 < 16; ++k4) {
                float4 v = *(const float4*)(x + k4 * 4);
                acc += v.x * ws[k4 * 4] + v.y * ws[k4 * 4 + 1] +
                       v.z * ws[k4 * 4 + 2] + v.w * ws[k4 * 4 + 3];
            }
            float t = (acc + b) * 0.01f;
            s = 1.0f / (1.0f + expf(-t));
        }
        ss[i] = s;
    }
    __syncthreads();

    const int i = blockIdx.x * 256 + threadIdx.x;
    if (i >= n) return;
    const float si = ss[i];
    int rank = 0;
    const int n4 = npad >> 2;
    for (int j4 = 0; j4 < n4; ++j4) {
        float4 v = *(const float4*)&ss[j4 * 4];
        int jb = j4 * 4;
        rank += (v.x > si) + (v.y > si) + (v.z > si) + (v.w > si);
        rank += (v.x == si && (jb + 0) < i);
        rank += (v.y == si && (jb + 1) < i);
        rank += (v.z == si && (jb + 2) < i);
        rank += (v.w == si && (jb + 3) < i);
    }
    if (rank < ksel) {
        Inew[rank] = Iold ? Iold[i] : i;
        const float* xi = X + (size_t)i * 64;
        float* xo = Xp + (size_t)rank * 64;
#pragma unroll
        for (int c4 = 0; c4 < 16; ++c4) {
            float4 v = *(const float4*)(xi + c4 * 4);
            v.x *= si; v.y *= si; v.z *= si; v.w *= si;
            *(float4*)(xo + c4 * 4) = v;
        }
    }
}

// --------------------------------------------------------------------- host
static int choose_split(int rows, size_t pbytes)
{
    int br = (rows + BM - 1) / BM;
    int sk = 1;
    while (sk < 32 && br * (sk * 2) <= 1024 &&
           (size_t)(sk * 2) * rows * 64 * 4 <= pbytes)
        sk *= 2;
    return sk;
}

extern "C" void kernel_launch(void* const* d_in, const int* in_sizes, int n_in,
                              void* d_out, int out_size, void* d_ws,
                              size_t ws_size, hipStream_t stream)
{
    const float* A   = (const float*)d_in[0];
    const float* X0  = (const float*)d_in[1];
    const float* Wst = (const float*)d_in[2];
    const float* bst = (const float*)d_in[3];
    const float* Wdn = (const float*)d_in[4];   // [4][64][64]
    const float* bdn = (const float*)d_in[5];   // [4][64]
    const float* Wpl = (const float*)d_in[6];   // [4][64]
    const float* bpl = (const float*)d_in[7];   // [4]
    const float* Wbt = (const float*)d_in[8];
    const float* bbt = (const float*)d_in[9];
    const float* Wup = (const float*)d_in[10];  // [4][64][64]
    const float* bup = (const float*)d_in[11];  // [4][64]
    const float* Wen = (const float*)d_in[12];  // [128][64]
    const float* ben = (const float*)d_in[13];

    float* out  = (float*)d_out;
    float* OUT2 = out + (size_t)N0 * 64;        // start_gcn_outs (= org_X)

    char* ws = (char*)d_ws;
    const size_t XBYTES = (size_t)N0 * 64 * 4;  // 2 MB
    float* Zn = (float*)(ws + 0 * XBYTES);
    float* XA = (float*)(ws + 1 * XBYTES);
    float* XB = (float*)(ws + 2 * XBYTES);
    float* D0 = (float*)(ws + 3 * XBYTES);
    float* D1 = (float*)(ws + 4 * XBYTES);
    float* D2 = (float*)(ws + 5 * XBYTES);
    float* D3 = (float*)(ws + 6 * XBYTES);
    int* I1 = (int*)(ws + 7 * XBYTES);
    int* I2 = I1 + N0;
    int* I3 = I2 + N0;
    int* I4 = I3 + N0;
    float* P = (float*)(ws + 7 * XBYTES + (size_t)N0 * 4 * 4);
    size_t pbytes = ws_size - (7 * XBYTES + (size_t)N0 * 4 * 4);

    // One GCN layer: Xout = A0[gidx] @ scatter(Xin @ W1 (+X2@W2)) + bias (+resid)
    auto gcn = [&](const float* Xin, int rin, const int* sidx,
                   const float* W1, const float* Xin2, const float* W2,
                   const int* gidx, int rout,
                   const float* bias, const float* resid, float* Xout) {
        if (sidx) hipMemsetAsync(Zn, 0, XBYTES, stream);
        k_small_gemm<<<(rin + 31) / 32, 256, 0, stream>>>(Xin, W1, Xin2, W2,
                                                          sidx, Zn, rin);
        int sk = choose_split(rout, pbytes);
        dim3 g((rout + BM - 1) / BM, sk);
        k_big_gemm<<<g, 256, 0, stream>>>(A, Zn, gidx, P, rout, N0 / sk);
        k_reduce<<<((rout * 16) + 255) / 256, 256, 0, stream>>>(
            P, sk, rout, bias, resid, Xout);
    };

    auto poolc = [&](const float* Xlv, int lvl, int n, int ksel,
                     const int* Iold, int* Inew, float* Xp) {
        int npad = (n + 3) & ~3;
        k_pool_rank<<<(n + 255) / 256, 256, npad * 4, stream>>>(
            Xlv, Wpl + lvl * 64, bpl + lvl, n, ksel, Iold, Xp, Inew);
    };

    // sizes: 8192 -> 7372 -> 5160 -> 3096 -> 1548  (int(KS[i]*n) chain)
    // start (also writes org_X / second output)
    gcn(X0, 8192, nullptr, Wst, nullptr, nullptr, nullptr, 8192, bst, nullptr, OUT2);
    // down 0..3 with pools
    gcn(OUT2, 8192, nullptr, Wdn + 0 * 4096, nullptr, nullptr, nullptr, 8192,
        bdn + 0 * 64, nullptr, D0);
    poolc(D0, 0, 8192, 7372, nullptr, I1, XA);
    gcn(XA, 7372, I1, Wdn + 1 * 4096, nullptr, nullptr, I1, 7372,
        bdn + 1 * 64, nullptr, D1);
    poolc(D1, 1, 7372, 5160, I1, I2, XB);
    gcn(XB, 5160, I2, Wdn + 2 * 4096, nullptr, nullptr, I2, 5160,
        bdn + 2 * 64, nullptr, D2);
    poolc(D2, 2, 5160, 3096, I2, I3, XA);
    gcn(XA, 3096, I3, Wdn + 3 * 4096, nullptr, nullptr, I3, 3096,
        bdn + 3 * 64, nullptr, D3);
    poolc(D3, 3, 3096, 1548, I3, I4, XB);
    // bottom
    gcn(XB, 1548, I4, Wbt, nullptr, nullptr, I4, 1548, bbt, nullptr, XA);
    // up (reverse levels, residual = down_outs)
    gcn(XA, 1548, I4, Wup + 0 * 4096, nullptr, nullptr, I3, 3096,
        bup + 0 * 64, D3, XB);
    gcn(XB, 3096, I3, Wup + 1 * 4096, nullptr, nullptr, I2, 5160,
        bup + 1 * 64, D2, XA);
    gcn(XA, 5160, I2, Wup + 2 * 4096, nullptr, nullptr, I1, 7372,
        bup + 2 * 64, D1, XB);
    gcn(XB, 7372, I1, Wup + 3 * 4096, nullptr, nullptr, nullptr, 8192,
        bup + 3 * 64, D0, XA);
    // end: A @ (X @ Wen[0:64] + org_X @ Wen[64:128]) + ben
    gcn(XA, 8192, nullptr, Wen, OUT2, Wen + 64 * 64, nullptr, 8192,
        ben, nullptr, out);
}